// Round 8
// baseline (41.089 us; speedup 1.0000x reference)
//
#include <hip/hip_runtime.h>

// GatedBlock: B=16, C=128, T=64, F=128, S=62, dilation=2, fp32 in/out.
// out[b,c,s,f] = (tanh(x0*wt0+x1*wt1+bt) * sigmoid(x0*ws0+x1*ws1+bs)
//                 + sum_t x[b,c,t,f]*w_res[s,t] + b_res[s]) * w_out[c] + b_out[c]
//
// Round 8: occupancy step-function. waves/SIMD steps at VGPR 64/128, so target
// VGPR<=64 AND LDS<=20KB for 8 blocks/CU (2x round 7's residency):
//  - prep kernel (round-3 verified) packs w_res -> bf16 A-frags + padded b_res
//    into d_ws; main kernel LDS = bf16 transposed x tile only (18432 B).
//  - ct-split main loop: only acc[4] (16 VGPR) + streamed A-frags (L2-hot ws,
//    global dwordx4) live post-barrier; stage regs die at the barrier.
//  - numerics identical to passing round 7 (same frag conventions, swizzle,
//    epilogue); absmax expected 0.0625.

typedef __attribute__((ext_vector_type(8)))  short short8;
typedef __attribute__((ext_vector_type(4)))  float f32x4;
typedef __attribute__((ext_vector_type(4)))  int   i32x4;
typedef __attribute__((ext_vector_type(2)))  int   i32x2;

constexpr int Bc = 16, Cc = 128, Tc = 64, Fc = 128, Sc = 62, DIL = 2;
constexpr int LDSTW    = 72;                  // bf16 elems per xT f-row
constexpr int XT_BYTES = Fc * LDSTW * 2;      // 18432

__device__ inline unsigned cvt_pk_bf16(float lo, float hi) {
    unsigned r;
    asm("v_cvt_pk_bf16_f32 %0, %1, %2" : "=v"(r) : "v"(lo), "v"(hi));
    return r;   // low16 = bf16(lo), high16 = bf16(hi), RNE
}

__device__ inline float bf16_lo(int u) { return __uint_as_float(((unsigned)u) << 16); }
__device__ inline float bf16_hi(int u) { return __uint_as_float(((unsigned)u) & 0xFFFF0000u); }

// ---- prep: pack w_res into A-fragment order (bf16), pad b_res to 64 ----
// ws layout: [0,8192): 8 frags (rt*2+kt) x 64 lanes x 16B; lane (g,r16) of
// frag (rt,kt) holds row=16rt+r16, k=32kt+8g+[0..7] as (k,k+1) bf16 pairs.
//            [8192, 8448): b_res padded to 64 floats (zeros past 61).
__global__ void prep_kernel(const float* __restrict__ w_res,
                            const float* __restrict__ b_res,
                            void* __restrict__ ws)
{
    const int tid = threadIdx.x;
    i32x4* wa = (i32x4*)ws;
    float* brs = (float*)((char*)ws + 8192);
    for (int u = tid; u < 512; u += 256) {
        const int frag = u >> 6, lane = u & 63;
        const int rt = frag >> 1, kt = frag & 1;
        const int row = 16 * rt + (lane & 15);
        const int g = lane >> 4;
        unsigned p[4];
#pragma unroll
        for (int q = 0; q < 4; ++q) {
            float lo = 0.f, hi = 0.f;
            if (row < Sc) {
                const int k = 32 * kt + 8 * g + 2 * q;
                lo = w_res[row * Tc + k];
                hi = w_res[row * Tc + k + 1];
            }
            p[q] = cvt_pk_bf16(lo, hi);
        }
        wa[u] = i32x4{(int)p[0], (int)p[1], (int)p[2], (int)p[3]};
    }
    if (tid < 64) brs[tid] = (tid < Sc) ? b_res[tid] : 0.f;
}

// ---- main ----
__global__ __launch_bounds__(256, 8)
void gated_mfma_kernel(const float* __restrict__ x,
                       const float* __restrict__ w_tanh,
                       const float* __restrict__ b_tanh,
                       const float* __restrict__ w_sig,
                       const float* __restrict__ b_sig,
                       const float* __restrict__ w_out,
                       const float* __restrict__ b_out,
                       const void* __restrict__ ws,
                       float* __restrict__ out)
{
    __shared__ i32x4 smem[XT_BYTES / 16];     // 18432 B, xT only
    char* lds_base = (char*)smem;

    const int bc   = blockIdx.x;              // (b,c) pair
    const int c    = bc & (Cc - 1);
    const int tid  = threadIdx.x;
    const int lane = tid & 63;
    const int w    = tid >> 6;                // wave 0..3 -> col-tiles 2w,2w+1
    const int g    = lane >> 4;               // lane group 0..3
    const int r16  = lane & 15;

    // Per-channel scalars: blockIdx-uniform -> SGPRs.
    const float wt0 = w_tanh[2 * c + 0], wt1 = w_tanh[2 * c + 1], bt = b_tanh[c];
    const float ws0 = w_sig[2 * c + 0],  ws1 = w_sig[2 * c + 1],  bs = b_sig[c];
    const float wo  = w_out[c],          bo  = b_out[c];

    // ---- stage x: thread (fq,tg) loads 8t x 4f block, coalesced dwordx4 ----
    const int fq = tid & 31;                   // f = 4*fq .. 4*fq+3
    const int tg = tid >> 5;                   // t = 8*tg .. 8*tg+7
    const float* xp = x + (size_t)bc * (Tc * Fc);
    f32x4 v[8];
#pragma unroll
    for (int u = 0; u < 8; ++u)
        v[u] = *(const f32x4*)(xp + (8 * tg + u) * Fc + 4 * fq);

    // xT writes: 4 x ds_write_b128, swizzle t~ = t ^ 8*((f>>2)&3)
    const int tsw = 8 * (tg ^ (fq & 3));
#pragma unroll
    for (int fj = 0; fj < 4; ++fj) {
        const unsigned p0 = cvt_pk_bf16(v[0][fj], v[1][fj]);
        const unsigned p1 = cvt_pk_bf16(v[2][fj], v[3][fj]);
        const unsigned p2 = cvt_pk_bf16(v[4][fj], v[5][fj]);
        const unsigned p3 = cvt_pk_bf16(v[6][fj], v[7][fj]);
        *(i32x4*)(lds_base + ((4 * fq + fj) * LDSTW + tsw) * 2) =
            i32x4{(int)p0, (int)p1, (int)p2, (int)p3};
    }

    __syncthreads();

    const short8* wa  = (const short8*)ws;                       // A-frags
    const float*  brs = (const float*)((const char*)ws + 8192);  // padded b_res

    const int col0 = 32 * w + r16;
    const int swz8 = 8 * (g ^ (r16 >> 2));     // B-frag t-swizzle bits
    const int sw8  = 8 * (r16 >> 2);           // epilogue tap swizzle bits
    float* op = out + (size_t)bc * (Sc * Fc);

#pragma unroll
    for (int ct = 0; ct < 2; ++ct) {
        const int col = col0 + 16 * ct;

        // acc init = b_res[row] (C-operand of MFMA); zeros past 61 in ws.
        f32x4 acc[4];
#pragma unroll
        for (int rt = 0; rt < 4; ++rt)
            acc[rt] = *(const f32x4*)(brs + 16 * rt + 4 * g);

        // MFMA: stream A from L2-hot ws; B one ds_read_b128 per kt.
#pragma unroll
        for (int kt = 0; kt < 2; ++kt) {
            const short8 Bf = *(const short8*)(lds_base +
                                (col * LDSTW + 32 * kt + swz8) * 2);
#pragma unroll
            for (int rt = 0; rt < 4; ++rt)
                acc[rt] = __builtin_amdgcn_mfma_f32_16x16x32_bf16(
                    wa[(rt * 2 + kt) * 64 + lane], Bf, acc[rt], 0, 0, 0);
        }

        // epilogue for this ct: taps via 2 x ds_read_b64 bf16 per rt.
#pragma unroll
        for (int rt = 0; rt < 4; ++rt) {
            const int r0 = 16 * rt + 4 * g;
            const i32x2 d1 = *(const i32x2*)(lds_base + (col * LDSTW + (r0 ^ sw8)) * 2);
            const i32x2 d2 = *(const i32x2*)(lds_base + (col * LDSTW + ((r0 + 4) ^ sw8)) * 2);
            const float t0 = bf16_lo(d1.x);    // x[r0]
            const float t1 = bf16_hi(d1.x);    // x[r0+1]
            const float t2 = bf16_lo(d1.y);    // x[r0+2]
            const float t3 = bf16_hi(d1.y);    // x[r0+3]
            const float t4 = bf16_lo(d2.x);    // x[r0+4] (garbage if >=64: masked)
            const float t5 = bf16_hi(d2.x);    // x[r0+5]

#define GATE_OUT(reg, xa, xb)                                                     \
            if (r0 + (reg) < Sc) {                                                \
                const float xt  = fmaf((xa), wt0, fmaf((xb), wt1, bt));           \
                const float xsg = fmaf((xa), ws0, fmaf((xb), ws1, bs));           \
                const float e2  = __expf(2.0f * xt);                              \
                const float em  = __expf(-xsg);                                   \
                const float gate = (e2 - 1.0f) *                                  \
                    __builtin_amdgcn_rcpf((e2 + 1.0f) * (1.0f + em));             \
                op[(r0 + (reg)) * Fc + col] =                                     \
                    fmaf(gate + acc[rt][reg], wo, bo);                            \
            }
            GATE_OUT(0, t0, t2)
            GATE_OUT(1, t1, t3)
            GATE_OUT(2, t2, t4)
            GATE_OUT(3, t3, t5)
#undef GATE_OUT
        }
    }
}

extern "C" void kernel_launch(void* const* d_in, const int* in_sizes, int n_in,
                              void* d_out, int out_size, void* d_ws, size_t ws_size,
                              hipStream_t stream)
{
    const float* x      = (const float*)d_in[0];
    const float* w_tanh = (const float*)d_in[1];
    const float* b_tanh = (const float*)d_in[2];
    const float* w_sig  = (const float*)d_in[3];
    const float* b_sig  = (const float*)d_in[4];
    const float* w_out  = (const float*)d_in[5];
    const float* b_out  = (const float*)d_in[6];
    const float* w_res  = (const float*)d_in[7];
    const float* b_res  = (const float*)d_in[8];
    // d_in[9] = dilation (==2) -> compile-time DIL.

    float* out = (float*)d_out;

    prep_kernel<<<1, 256, 0, stream>>>(w_res, b_res, d_ws);
    gated_mfma_kernel<<<Bc * Cc, 256, 0, stream>>>(
        x, w_tanh, b_tanh, w_sig, b_sig, w_out, b_out, d_ws, out);
}